// Round 9
// baseline (237.273 us; speedup 1.0000x reference)
//
#include <hip/hip_runtime.h>
#include <hip/hip_bf16.h>
#include <math.h>

// GQA forward, round 9: 3-kernel pipeline.
//  [qkv_fused]  f32 x,W read + in-staging bf16 convert + MFMA GEMM +
//               epilogue RMSNorm/RoPE + direct Qb/Kf/Vf layout writes
//               (kills prep, norm_rope_tv, Tq and xb round-trips)
//  [flash]      unchanged round-8 (XCD-pinned, fixed-max exp2 softmax)
//  [proj_fused] MFMA GEMM, A=bf16 Ob, W=f32 converted in staging, f32 out.

#define N_SEQ 2048
#define EMB   1024
#define NH    16
#define NKV   4
#define HD    64
#define BATCH 2
#define M_TOT 4096
#define QSCALE (0.125f * 1.44269504f)

typedef __attribute__((ext_vector_type(8)))  short short8;   // 8 bf16
typedef __attribute__((ext_vector_type(4)))  float f32x4;
typedef __attribute__((ext_vector_type(16))) float f32x16;

__device__ __forceinline__ ushort f2bf(float f) {
    union { __hip_bfloat16 h; ushort u; } cv;
    cv.h = __float2bfloat16(f);
    return cv.u;
}
__device__ __forceinline__ uint pack2bf(float a, float b) {
    union { __hip_bfloat162 h; uint u; } cv;
    cv.h = __float22bfloat162_rn(float2{a, b});   // a -> low16, b -> high16
    return cv.u;
}
__device__ __forceinline__ short8 pack8(float4 a, float4 b) {
    union { uint u[4]; short8 s; } r;
    r.u[0] = pack2bf(a.x, a.y);
    r.u[1] = pack2bf(a.z, a.w);
    r.u[2] = pack2bf(b.x, b.y);
    r.u[3] = pack2bf(b.z, b.w);
    return r.s;
}

// ---------------------------------------------------------------------------
// Fused QKV GEMM + RMSNorm + RoPE + layout writes.
// Grid (12, 64): bx = 128-col tile (0-7 Q, 8-9 K, 10-11 V), by = 64-row tile.
// 4 waves: wave = 32m x 64n -> each wave's 64 cols = exactly one head.
// Staging converts f32->bf16 in-register (no prep kernel, no xb).
// ---------------------------------------------------------------------------
__global__ __launch_bounds__(256) void qkv_fused_kernel(
    const float* __restrict__ x,  const float* __restrict__ wq,
    const float* __restrict__ wk, const float* __restrict__ wv,
    const float* __restrict__ bq, const float* __restrict__ bk,
    const float* __restrict__ bv, const float* __restrict__ qn_w,
    const float* __restrict__ kn_w, const float* __restrict__ sinp,
    const float* __restrict__ cosp, ushort* __restrict__ Qb,
    ushort* __restrict__ Kf, ushort* __restrict__ Vf)
{
    __shared__ ushort smem[8192];        // As 64x40 @0, Bs 128x40 @2560 (15KB);
    ushort* As = smem;                   // V-epilogue reuses all 16KB
    ushort* Bs = smem + 2560;

    const int tid = threadIdx.x;
    const int bx = blockIdx.x;           // 0..11
    const int m0 = blockIdx.y * 64;
    const int w = tid >> 6, lane = tid & 63;
    const int quad = lane >> 4, l16 = lane & 15;
    const int wm = (w & 1) * 32, wn = (w >> 1) * 64;

    const float* Wsrc; const float* bsrc; int nbase;
    if (bx < 8)       { Wsrc = wq; bsrc = bq; nbase = bx * 128; }
    else if (bx < 10) { Wsrc = wk; bsrc = bk; nbase = bx * 128 - 1024; }
    else              { Wsrc = wv; bsrc = bv; nbase = bx * 128 - 1280; }

    f32x4 acc[2][4] = {};

    float bb[4];
#pragma unroll
    for (int j = 0; j < 4; ++j) bb[j] = bsrc[nbase + wn + j * 16 + l16];

    const int r0 = tid >> 2;             // 0..63
    const int c0 = (tid & 3) * 8;        // k-chunk (8 elems)
    const float* Ap = x    + (size_t)(m0 + r0) * EMB + c0;
    const float* Wp = Wsrc + (size_t)(nbase + r0) * EMB + c0;

    for (int k0 = 0; k0 < EMB; k0 += 32) {
        const float4 af0 = *(const float4*)(Ap + k0);
        const float4 af1 = *(const float4*)(Ap + k0 + 4);
        const float4 bf0 = *(const float4*)(Wp + k0);
        const float4 bf1 = *(const float4*)(Wp + k0 + 4);
        const float4 bg0 = *(const float4*)(Wp + (size_t)64 * EMB + k0);
        const float4 bg1 = *(const float4*)(Wp + (size_t)64 * EMB + k0 + 4);
        __syncthreads();
        *(short8*)&As[r0 * 40 + c0] = pack8(af0, af1);
        *(short8*)&Bs[r0 * 40 + c0] = pack8(bf0, bf1);
        *(short8*)&Bs[(r0 + 64) * 40 + c0] = pack8(bg0, bg1);
        __syncthreads();

        short8 aF[2], bF[4];
#pragma unroll
        for (int i = 0; i < 2; ++i)
            aF[i] = *(const short8*)&As[(wm + i * 16 + l16) * 40 + quad * 8];
#pragma unroll
        for (int j = 0; j < 4; ++j)
            bF[j] = *(const short8*)&Bs[(wn + j * 16 + l16) * 40 + quad * 8];
#pragma unroll
        for (int i = 0; i < 2; ++i)
#pragma unroll
            for (int j = 0; j < 4; ++j)
                acc[i][j] = __builtin_amdgcn_mfma_f32_16x16x32_bf16(
                    aF[i], bF[j], acc[i][j], 0, 0, 0);
    }

    const int hloc = wn >> 6;            // 0/1: which head of the tile

    if (bx < 10) {
        // ---- Q / K path: RMSNorm + RoPE in-register ----
        const float* nwp = (bx < 8) ? qn_w : kn_w;
        const float oscale = (bx < 8) ? QSCALE : 1.0f;
        float wreg[4];
#pragma unroll
        for (int j = 0; j < 4; ++j) wreg[j] = nwp[j * 16 + l16];

#pragma unroll
        for (int i = 0; i < 2; ++i)
#pragma unroll
            for (int r = 0; r < 4; ++r) {
                const int m = m0 + wm + i * 16 + quad * 4 + r;
                const int n = m & (N_SEQ - 1), b = m >> 11;
                float v[4], vn[4];
                float ssum = 0.0f;
#pragma unroll
                for (int j = 0; j < 4; ++j) {
                    v[j] = acc[i][j][r] + bb[j];
                    ssum += v[j] * v[j];
                }
#pragma unroll
                for (int mask = 1; mask <= 8; mask <<= 1)
                    ssum += __shfl_xor(ssum, mask, 64);
                const float rr = rsqrtf(ssum * (1.0f / 64.0f) + 1e-6f);
#pragma unroll
                for (int j = 0; j < 4; ++j) vn[j] = v[j] * rr * wreg[j];
#pragma unroll
                for (int j = 0; j < 4; ++j) {
                    const int d = j * 16 + l16;
                    const float rot = (j < 2) ? -vn[j + 2] : vn[j - 2];
                    const float out =
                        (vn[j] * cosp[n * HD + d] + rot * sinp[n * HD + d]) * oscale;
                    if (bx < 8) {
                        const int h = bx * 2 + hloc;
                        Qb[((size_t)(b * NH + h) * N_SEQ + n) * HD + d] = f2bf(out);
                    } else {
                        const int kvh = (bx - 8) * 2 + hloc;
                        const int kt = n >> 6, rk = n & 63, s2 = rk >> 5, l32k = rk & 31;
                        const int c2 = d >> 4, l5k = (d >> 3) & 1, jj = d & 7;
                        Kf[((size_t)(b * NKV + kvh) * 32 + kt) * 4096
                           + (s2 * 4 + c2) * 512 + l32k * 16 + l5k * 8 + jj] = f2bf(out);
                    }
                }
            }
    } else {
        // ---- V path: bias add, LDS transpose, frag-order write ----
        __syncthreads();                 // all waves done reading As/Bs
#pragma unroll
        for (int i = 0; i < 2; ++i)
#pragma unroll
            for (int j = 0; j < 4; ++j)
#pragma unroll
                for (int r = 0; r < 4; ++r) {
                    const int tok = wm + i * 16 + quad * 4 + r;   // 0..63
                    const int d = j * 16 + l16;
                    smem[hloc * 4096 + tok * 64 + d] = f2bf(acc[i][j][r] + bb[j]);
                }
        __syncthreads();

        const int b = m0 >> 11;
        const int kt = (m0 & (N_SEQ - 1)) >> 6;
#pragma unroll
        for (int t = 0; t < 4; ++t) {
            const int idx = tid + t * 256;     // short8-unit index 0..1023
            const int e = idx * 8;
            const int kv2 = e >> 12;           // 0/1
            const int rem = e & 4095;          // chunk-relative element base
            const int ci = rem >> 9;           // (ss*2+tt)*2+d2
            const int w512 = rem & 511;
            const int l32v = w512 >> 4;
            const int l5v = (w512 >> 3) & 1;
            const int d2 = ci & 1;
            const int sstt = ci >> 1;
            const int keyb = sstt * 16 + l5v * 8;   // local key base
            const int d = d2 * 32 + l32v;
            short8 o;
#pragma unroll
            for (int e8 = 0; e8 < 8; ++e8)
                o[e8] = (short)smem[kv2 * 4096 + (keyb + e8) * 64 + d];
            const int kvAbs = (bx - 10) * 2 + kv2;
            *(short8*)&Vf[((size_t)(b * NKV + kvAbs) * 32 + kt) * 4096 + rem] = o;
        }
    }
}

// ---------------------------------------------------------------------------
// Barrier-free flash (unchanged round 8): fixed-max exp2 softmax, XCD-pinned
// 1-D grid (1024): bh = (blk&7) + 8*((blk>>3)>>5), qt = (blk>>3)&31.
// ---------------------------------------------------------------------------
__global__ __launch_bounds__(256, 4) void flash_mfma32_kernel(
    const ushort* __restrict__ Qb, const ushort* __restrict__ Kf,
    const ushort* __restrict__ Vf, ushort* __restrict__ Ob)
{
    __shared__ float fsm[4352];

    const int blk = blockIdx.x;
    const int xcd = blk & 7;
    const int wi = blk >> 3;
    const int bh = xcd + 8 * (wi >> 5);
    const int qt = wi & 31;
    const int b = bh >> 4, h = bh & 15;
    const int kvh = h >> 2;
    const int tid = threadIdx.x;
    const int w = tid >> 6, lane = tid & 63;
    const int l32 = lane & 31, l5 = lane >> 5;
    const int qg = w & 1;
    const int kh = w >> 1;

    const ushort* Qg = Qb + ((size_t)bh * N_SEQ + qt * 64 + qg * 32) * HD;
    const size_t kvbase = (size_t)(b * NKV + kvh) * (32 * 4096);
    const ushort* Kp = Kf + kvbase + (size_t)kh * 16 * 4096;
    const ushort* Vp = Vf + kvbase + (size_t)kh * 16 * 4096;
    const int loff = l32 * 16 + l5 * 8;

    short8 qF[4];
#pragma unroll
    for (int c = 0; c < 4; ++c)
        qF[c] = *(const short8*)&Qg[(size_t)l32 * HD + c * 16 + l5 * 8];

    f32x16 Oa[2] = {};
    float lrow = 0.0f;

    short8 kN[2][4];
#pragma unroll
    for (int s = 0; s < 2; ++s)
#pragma unroll
        for (int c = 0; c < 4; ++c)
            kN[s][c] = *(const short8*)&Kp[(s * 4 + c) * 512 + loff];

    for (int i = 0; i < 16; ++i) {
        short8 kC[2][4];
#pragma unroll
        for (int s = 0; s < 2; ++s)
#pragma unroll
            for (int c = 0; c < 4; ++c) kC[s][c] = kN[s][c];

        const ushort* Vt = Vp + i * 4096;
        short8 vT[2][2][2];
#pragma unroll
        for (int s = 0; s < 2; ++s)
#pragma unroll
            for (int t = 0; t < 2; ++t)
#pragma unroll
                for (int d2 = 0; d2 < 2; ++d2)
                    vT[s][t][d2] = *(const short8*)&Vt[((s * 2 + t) * 2 + d2) * 512 + loff];

        if (i + 1 < 16) {
            const ushort* Kt = Kp + (i + 1) * 4096;
#pragma unroll
            for (int s = 0; s < 2; ++s)
#pragma unroll
                for (int c = 0; c < 4; ++c)
                    kN[s][c] = *(const short8*)&Kt[(s * 4 + c) * 512 + loff];
        }

        f32x16 Sv[2] = {};
#pragma unroll
        for (int s = 0; s < 2; ++s)
#pragma unroll
            for (int c = 0; c < 4; ++c)
                Sv[s] = __builtin_amdgcn_mfma_f32_32x32x16_bf16(kC[s][c], qF[c], Sv[s], 0, 0, 0);

        float rs = 0.0f;
#pragma unroll
        for (int s = 0; s < 2; ++s)
#pragma unroll
            for (int r = 0; r < 16; ++r) {
                Sv[s][r] = __builtin_amdgcn_exp2f(Sv[s][r]);
                rs += Sv[s][r];
            }
        lrow += rs;

        uint P2[2][8];
#pragma unroll
        for (int s = 0; s < 2; ++s)
#pragma unroll
            for (int g = 0; g < 4; ++g)
#pragma unroll
                for (int hh = 0; hh < 2; ++hh)
                    P2[s][g * 2 + hh] =
                        pack2bf(Sv[s][4 * g + 2 * hh], Sv[s][4 * g + 2 * hh + 1]);

#pragma unroll
        for (int s = 0; s < 2; ++s)
#pragma unroll
            for (int t = 0; t < 2; ++t) {
                const uint snd0 = l5 ? P2[s][4 * t + 0] : P2[s][4 * t + 2];
                const uint snd1 = l5 ? P2[s][4 * t + 1] : P2[s][4 * t + 3];
                const uint kp0  = l5 ? P2[s][4 * t + 2] : P2[s][4 * t + 0];
                const uint kp1  = l5 ? P2[s][4 * t + 3] : P2[s][4 * t + 1];
                const uint rcv0 = __shfl_xor(snd0, 32, 64);
                const uint rcv1 = __shfl_xor(snd1, 32, 64);
                union { uint u[4]; short8 s8; } pb;
                pb.u[0] = l5 ? rcv0 : kp0;
                pb.u[1] = l5 ? rcv1 : kp1;
                pb.u[2] = l5 ? kp0 : rcv0;
                pb.u[3] = l5 ? kp1 : rcv1;
#pragma unroll
                for (int d2 = 0; d2 < 2; ++d2)
                    Oa[d2] = __builtin_amdgcn_mfma_f32_32x32x16_bf16(
                        vT[s][t][d2], pb.s8, Oa[d2], 0, 0, 0);
            }
    }

    lrow += __shfl_xor(lrow, 32, 64);

    float* buf = fsm + qg * 2112;
    if (kh == 1) {
#pragma unroll
        for (int d2 = 0; d2 < 2; ++d2)
#pragma unroll
            for (int r = 0; r < 16; ++r)
                buf[(d2 * 16 + r) * 64 + lane] = Oa[d2][r];
        buf[2048 + lane] = lrow;
    }
    __syncthreads();

    if (kh == 0) {
        lrow += buf[2048 + lane];
#pragma unroll
        for (int d2 = 0; d2 < 2; ++d2)
#pragma unroll
            for (int r = 0; r < 16; ++r)
                Oa[d2][r] += buf[(d2 * 16 + r) * 64 + lane];
    }
    __syncthreads();

    ushort* Os = (ushort*)fsm;
    if (kh == 0) {
        const float inv = 1.0f / lrow;
#pragma unroll
        for (int d2 = 0; d2 < 2; ++d2)
#pragma unroll
            for (int r = 0; r < 16; ++r) {
                const int d = d2 * 32 + (r & 3) + 8 * (r >> 2) + 4 * l5;
                Os[(qg * 32 + l32) * 68 + d] = f2bf(Oa[d2][r] * inv);
            }
    }
    __syncthreads();

    const int row = tid >> 2, cc = (tid & 3) * 16;
#pragma unroll
    for (int i = 0; i < 2; ++i) {
        const short8 v = *(const short8*)&Os[row * 68 + cc + i * 8];
        *(short8*)&Ob[((size_t)b * N_SEQ + qt * 64 + row) * EMB + h * HD + cc + i * 8] = v;
    }
}

// ---------------------------------------------------------------------------
// Output projection: A = Ob bf16, W = proj_w f32 (converted in staging),
// C = f32 out. 64x128 tile, grid (8, 64).
// ---------------------------------------------------------------------------
__global__ __launch_bounds__(256) void proj_fused_kernel(
    const ushort* __restrict__ A, const float* __restrict__ Wf,
    const float* __restrict__ bias, float* __restrict__ C)
{
    __shared__ ushort smem[7680];
    ushort* As = smem;                   // 64 x 40
    ushort* Bs = smem + 2560;            // 128 x 40

    const int tid = threadIdx.x;
    const int m0 = blockIdx.y * 64, n0 = blockIdx.x * 128;
    const int w = tid >> 6, lane = tid & 63;
    const int quad = lane >> 4, l16 = lane & 15;
    const int wm = (w & 1) * 32, wn = (w >> 1) * 64;

    f32x4 acc[2][4] = {};

    float bb[4];
#pragma unroll
    for (int j = 0; j < 4; ++j) bb[j] = bias[n0 + wn + j * 16 + l16];

    const int r0 = tid >> 2;
    const int c0 = (tid & 3) * 8;
    const ushort* Ap = A + (size_t)(m0 + r0) * EMB + c0;
    const float* Wp = Wf + (size_t)(n0 + r0) * EMB + c0;

    for (int k0 = 0; k0 < EMB; k0 += 32) {
        const short8 a0 = *(const short8*)(Ap + k0);
        const float4 bf0 = *(const float4*)(Wp + k0);
        const float4 bf1 = *(const float4*)(Wp + k0 + 4);
        const float4 bg0 = *(const float4*)(Wp + (size_t)64 * EMB + k0);
        const float4 bg1 = *(const float4*)(Wp + (size_t)64 * EMB + k0 + 4);
        __syncthreads();
        *(short8*)&As[r0 * 40 + c0] = a0;
        *(short8*)&Bs[r0 * 40 + c0] = pack8(bf0, bf1);
        *(short8*)&Bs[(r0 + 64) * 40 + c0] = pack8(bg0, bg1);
        __syncthreads();

        short8 aF[2], bF[4];
#pragma unroll
        for (int i = 0; i < 2; ++i)
            aF[i] = *(const short8*)&As[(wm + i * 16 + l16) * 40 + quad * 8];
#pragma unroll
        for (int j = 0; j < 4; ++j)
            bF[j] = *(const short8*)&Bs[(wn + j * 16 + l16) * 40 + quad * 8];
#pragma unroll
        for (int i = 0; i < 2; ++i)
#pragma unroll
            for (int j = 0; j < 4; ++j)
                acc[i][j] = __builtin_amdgcn_mfma_f32_16x16x32_bf16(
                    aF[i], bF[j], acc[i][j], 0, 0, 0);
    }

#pragma unroll
    for (int i = 0; i < 2; ++i) {
        const int rowb = m0 + wm + i * 16 + quad * 4;
#pragma unroll
        for (int j = 0; j < 4; ++j) {
            const int col = n0 + wn + j * 16 + l16;
#pragma unroll
            for (int r = 0; r < 4; ++r)
                C[(size_t)(rowb + r) * EMB + col] = acc[i][j][r] + bb[j];
        }
    }
}

// ---------------------------------------------------------------------------
extern "C" void kernel_launch(void* const* d_in, const int* in_sizes, int n_in,
                              void* d_out, int out_size, void* d_ws, size_t ws_size,
                              hipStream_t stream)
{
    const float* x      = (const float*)d_in[0];
    const float* sinp   = (const float*)d_in[1];
    const float* cosp   = (const float*)d_in[2];
    const float* wq_w   = (const float*)d_in[3];
    const float* wq_b   = (const float*)d_in[4];
    const float* wk_w   = (const float*)d_in[5];
    const float* wk_b   = (const float*)d_in[6];
    const float* wv_w   = (const float*)d_in[7];
    const float* wv_b   = (const float*)d_in[8];
    const float* qn_w   = (const float*)d_in[9];
    const float* kn_w   = (const float*)d_in[10];
    const float* proj_w = (const float*)d_in[11];
    const float* proj_b = (const float*)d_in[12];
    float* out = (float*)d_out;

    // workspace (ushort units) — Qb 8MB, Kf 2MB, Vf 2MB, Ob 8MB = 20MB
    ushort* Qb = (ushort*)d_ws;              // 2*16*2048*64
    ushort* Kf = Qb + 4194304;               // frag-order K
    ushort* Vf = Kf + 1048576;               // frag-order V^T
    ushort* Ob = Vf + 1048576;               // attention out bf16 [4096][1024]

    qkv_fused_kernel<<<dim3(12, 64), 256, 0, stream>>>(
        x, wq_w, wk_w, wv_w, wq_b, wk_b, wv_b, qn_w, kn_w, sinp, cosp,
        Qb, Kf, Vf);

    flash_mfma32_kernel<<<1024, 256, 0, stream>>>(Qb, Kf, Vf, Ob);

    proj_fused_kernel<<<dim3(8, 64), 256, 0, stream>>>(Ob, proj_w, proj_b, out);
}